// Round 12
// baseline (292.392 us; speedup 1.0000x reference)
//
#include <hip/hip_runtime.h>

#define N_NODES 100000
#define E_EDGES 1600000
#define DIM     128

// Binning geometry:
//  coarse bucket = 256 nodes (dst>>8): 391 real buckets, padded 512
//  chunk = 4096 edges: 391 chunks (matches prep-hist blocks; pass1 reuse)
#define NB1     391            // level-1 chunks (4096 edges each)
#define CHUNK   4096
#define NBINS   512            // padded bucket count (actual 391)
#define NBUCKET 391
#define NBH     (NBINS * NB1)  // 200192 bin-major [bin][chunk] histogram entries
#define HS_BLOCKS 196          // ceil(NBH/1024)
#define LDSCAP  5120           // csr LDS stage capacity (avg bucket 4090, +16 sigma)

// Workspace layout (bytes), total ~66.1 MiB:
#define HB_OFF    0            // h packed bf16: N*64 u32 = 25,600,000
#define WTB_OFF   25600000     // WcatT bf16 B-fragment layout: 16384 u32 = 65,536
#define OFFS_OFF  25665536     // N+1 int (padded to 400,064)
#define BHC_OFF   26065600     // raw counts: NBH ints = 800,768 (pad 800,832)
#define BH_OFF    26866432     // scanned: NBH ints = 800,768
#define BSUM_OFF  27667200     // 196 ints (padded to 1024)
#define BIN_OFF   27668224     // E ints = 6,400,000
#define SRC_OFF   34068224     // E ints = 6,400,000
#define AGGB_OFF  40468224     // N*64 u32 = 25,600,000 -> end 66,068,224

typedef __attribute__((ext_vector_type(8))) short short8;
typedef __attribute__((ext_vector_type(4))) float floatx4;

// ---------- bf16 pack/unpack (RNE) ----------
__device__ __forceinline__ unsigned bf16pack(float a, float b) {
  unsigned ua = __float_as_uint(a); ua += 0x7fffu + ((ua >> 16) & 1u);
  unsigned ub = __float_as_uint(b); ub += 0x7fffu + ((ub >> 16) & 1u);
  return (ua >> 16) | (ub & 0xffff0000u);
}
__device__ __forceinline__ float2 bf16unpack(unsigned p) {
  return make_float2(__uint_as_float(p << 16), __uint_as_float(p & 0xffff0000u));
}

// ------------- prep: LayerNorm+ReLU -> hb, weight pack, level-1 histogram ----
__global__ __launch_bounds__(256) void k_prep(const float* __restrict__ x,
                                              const float* __restrict__ lw,
                                              const float* __restrict__ lb,
                                              const float* __restrict__ Wl,
                                              const float* __restrict__ Wr,
                                              const int* __restrict__ ei,
                                              unsigned* __restrict__ hb,
                                              unsigned* __restrict__ wtb,
                                              int* __restrict__ bhc) {
  int gid = blockIdx.x * 256 + threadIdx.x;
  int t = threadIdx.x;

  // --- LN+ReLU ---
  {
    int row  = blockIdx.x * 4 + (t >> 6);
    int lane = t & 63;
    float2 v = ((const float2*)(x + (size_t)row * DIM))[lane];
    float s  = v.x + v.y;
    float sq = v.x * v.x + v.y * v.y;
    #pragma unroll
    for (int off = 32; off > 0; off >>= 1) {
      s  += __shfl_xor(s, off);
      sq += __shfl_xor(sq, off);
    }
    float mu  = s * (1.0f / 128.0f);
    float var = sq * (1.0f / 128.0f) - mu * mu;
    float rs  = rsqrtf(var + 1e-5f);
    float2 w = ((const float2*)lw)[lane];
    float2 b = ((const float2*)lb)[lane];
    float ox = fmaxf((v.x - mu) * rs * w.x + b.x, 0.0f);
    float oy = fmaxf((v.y - mu) * rs * w.y + b.y, 0.0f);
    hb[(size_t)row * 64 + lane] = bf16pack(ox, oy);
  }

  // --- weight pack (bf16, B-fragment layout) ---
  if (gid < 16384) {
    int j2 = gid & 3;
    int q  = (gid >> 2) & 3;
    int c  = (gid >> 4) & 127;
    int kb = gid >> 11;
    int k0 = kb * 32 + q * 8 + j2 * 2;
    int k1 = k0 + 1;
    float v0 = (k0 < 128) ? Wl[c * 128 + k0] : Wr[c * 128 + (k0 - 128)];
    float v1 = (k1 < 128) ? Wl[c * 128 + k1] : Wr[c * 128 + (k1 - 128)];
    wtb[gid] = bf16pack(v0, v1);
  }

  // --- level-1 histogram: chunk = 4096 edges (block-uniform branch) ---
  if (blockIdx.x < NB1) {
    __shared__ int h[NBINS];
    h[t] = 0; h[t + 256] = 0;
    __syncthreads();
    const int4* d4p = (const int4*)(ei + E_EDGES);
    #pragma unroll
    for (int u = 0; u < 4; ++u) {
      int i4 = blockIdx.x * (CHUNK / 4) + u * 256 + t;
      if (i4 < E_EDGES / 4) {
        int4 d = d4p[i4];
        atomicAdd(&h[d.x >> 8], 1);
        atomicAdd(&h[d.y >> 8], 1);
        atomicAdd(&h[d.z >> 8], 1);
        atomicAdd(&h[d.w >> 8], 1);
      }
    }
    __syncthreads();
    bhc[t * NB1 + blockIdx.x] = h[t];
    bhc[(t + 256) * NB1 + blockIdx.x] = h[t + 256];
  }
}

// ---------------- scan stage 1: bhc (counts) -> bh (block-local scans) -------
__global__ __launch_bounds__(256) void k_hscan1(const int* __restrict__ bhc,
                                                int* __restrict__ bh,
                                                int* __restrict__ bsum) {
  __shared__ int s[256];
  int t = threadIdx.x;
  int base = blockIdx.x * 1024 + t * 4;
  int a0 = (base + 0 < NBH) ? bhc[base + 0] : 0;
  int a1 = (base + 1 < NBH) ? bhc[base + 1] : 0;
  int a2 = (base + 2 < NBH) ? bhc[base + 2] : 0;
  int a3 = (base + 3 < NBH) ? bhc[base + 3] : 0;
  s[t] = a0 + a1 + a2 + a3;
  __syncthreads();
  #pragma unroll
  for (int off = 1; off < 256; off <<= 1) {
    int x = (t >= off) ? s[t - off] : 0;
    __syncthreads();
    s[t] += x;
    __syncthreads();
  }
  int excl = (t > 0) ? s[t - 1] : 0;
  if (t == 255) bsum[blockIdx.x] = s[255];
  if (base + 0 < NBH) bh[base + 0] = excl;
  if (base + 1 < NBH) bh[base + 1] = excl + a0;
  if (base + 2 < NBH) bh[base + 2] = excl + a0 + a1;
  if (base + 3 < NBH) bh[base + 3] = excl + a0 + a1 + a2;
}

// ------- level-1 bin-sort: reuses prep's histogram (NO pass-1 atomics) -------
__global__ __launch_bounds__(256) void k_binsort(const int* __restrict__ ei,
                                                 const int* __restrict__ bh,
                                                 const int* __restrict__ bhc,
                                                 const int* __restrict__ bsum,
                                                 int* __restrict__ binned) {
  __shared__ int stage[CHUNK];   // 16 KiB: bin-sorted packed edges
  __shared__ int addr[CHUNK];    // 16 KiB: final global index per staged edge
  __shared__ int hist[NBINS];    // chunk counts (loaded, not recomputed)
  __shared__ int ebase[NBINS];   // intra-chunk exclusive base per bin
  __shared__ int cur[NBINS];     // placement cursor
  __shared__ int gbase[NBINS];   // global base per (bin, chunk)
  __shared__ int s[256];
  __shared__ int bsc[256];       // exclusive scan of bsum (196 valid)
  int t  = threadIdx.x;
  int ch = blockIdx.x;

  // bsum exclusive scan (folded hscan2)
  s[t] = (t < HS_BLOCKS) ? bsum[t] : 0;
  __syncthreads();
  #pragma unroll
  for (int off = 1; off < 256; off <<= 1) {
    int xv = (t >= off) ? s[t - off] : 0;
    __syncthreads();
    s[t] += xv;
    __syncthreads();
  }
  bsc[t] = (t > 0) ? s[t - 1] : 0;
  __syncthreads();

  {
    int i0 = t * NB1 + ch;
    int i1 = (t + 256) * NB1 + ch;
    gbase[t]       = bh[i0] + bsc[i0 >> 10];
    gbase[t + 256] = bh[i1] + bsc[i1 >> 10];
    hist[t]        = bhc[i0];
    hist[t + 256]  = bhc[i1];
  }
  __syncthreads();

  // scan 512 bins via 256 pair-partials (no atomics)
  int h0 = hist[2 * t], h1 = hist[2 * t + 1];
  s[t] = h0 + h1;
  __syncthreads();
  #pragma unroll
  for (int off = 1; off < 256; off <<= 1) {
    int xv = (t >= off) ? s[t - off] : 0;
    __syncthreads();
    s[t] += xv;
    __syncthreads();
  }
  int ex = (t > 0) ? s[t - 1] : 0;
  ebase[2 * t] = ex;
  ebase[2 * t + 1] = ex + h0;
  cur[2 * t] = ex;
  cur[2 * t + 1] = ex + h0;
  __syncthreads();

  const int4* s4p = (const int4*)ei;
  const int4* d4p = (const int4*)(ei + E_EDGES);

  // place edges bin-sorted into LDS, record final global address
  #pragma unroll
  for (int u = 0; u < 4; ++u) {
    int i4 = ch * (CHUNK / 4) + u * 256 + t;
    if (i4 < E_EDGES / 4) {
      int4 sv = s4p[i4];
      int4 dv = d4p[i4];
      {
        int bin = dv.x >> 8; int pos = atomicAdd(&cur[bin], 1);
        stage[pos] = sv.x | ((dv.x & 255) << 20);
        addr[pos]  = gbase[bin] + (pos - ebase[bin]);
      }
      {
        int bin = dv.y >> 8; int pos = atomicAdd(&cur[bin], 1);
        stage[pos] = sv.y | ((dv.y & 255) << 20);
        addr[pos]  = gbase[bin] + (pos - ebase[bin]);
      }
      {
        int bin = dv.z >> 8; int pos = atomicAdd(&cur[bin], 1);
        stage[pos] = sv.z | ((dv.z & 255) << 20);
        addr[pos]  = gbase[bin] + (pos - ebase[bin]);
      }
      {
        int bin = dv.w >> 8; int pos = atomicAdd(&cur[bin], 1);
        stage[pos] = sv.w | ((dv.w & 255) << 20);
        addr[pos]  = gbase[bin] + (pos - ebase[bin]);
      }
    }
  }
  __syncthreads();

  // write-out: mostly-consecutive addresses (contiguous runs per bin)
  int cbase = ch * CHUNK;
  int cnt = E_EDGES - cbase;
  if (cnt > CHUNK) cnt = CHUNK;
  for (int i = t; i < cnt; i += 256)
    binned[addr[i]] = stage[i];
}

// ---- level-2 CSR + per-node src-sort (LDS-staged; unsorted global fallback) -
// Sorting each node's source list ascending makes concurrent gather waves
// sweep hb low->high quasi-coherently -> better per-XCD L2 hit rate.
// Order within a node does not affect mean-aggregation correctness.
__global__ __launch_bounds__(256) void k_csr(const int* __restrict__ bh,
                                             const int* __restrict__ bsum,
                                             const int* __restrict__ binned,
                                             int* __restrict__ offs,
                                             int* __restrict__ srcidx) {
  __shared__ int h[256];
  __shared__ int s[256];
  __shared__ int cur[256];
  __shared__ int bsc[256];
  __shared__ int stg[LDSCAP];    // 20 KiB: bucket edges
  __shared__ int stg2[LDSCAP];   // 20 KiB: node-grouped srcs
  int t = threadIdx.x;
  int bin = blockIdx.x;

  // bsum exclusive scan (folded hscan2)
  s[t] = (t < HS_BLOCKS) ? bsum[t] : 0;
  __syncthreads();
  #pragma unroll
  for (int off = 1; off < 256; off <<= 1) {
    int xv = (t >= off) ? s[t - off] : 0;
    __syncthreads();
    s[t] += xv;
    __syncthreads();
  }
  bsc[t] = (t > 0) ? s[t - 1] : 0;
  __syncthreads();

  int i0 = bin * NB1, i1 = (bin + 1) * NB1;
  int base = bh[i0] + bsc[i0 >> 10];
  int end  = (bin + 1 < NBINS) ? (bh[i1] + bsc[i1 >> 10]) : E_EDGES;
  int cnt  = end - base;

  h[t] = 0;
  __syncthreads();

  if (cnt <= LDSCAP) {
    // ---- LDS path: stage bucket, hist, scan, scatter, per-node sort ----
    for (int i = t; i < cnt; i += 256) stg[i] = binned[base + i];
    __syncthreads();
    for (int i = t; i < cnt; i += 256)
      atomicAdd(&h[(stg[i] >> 20) & 255], 1);
    __syncthreads();
    s[t] = h[t];
    __syncthreads();
    #pragma unroll
    for (int off = 1; off < 256; off <<= 1) {
      int x = (t >= off) ? s[t - off] : 0;
      __syncthreads();
      s[t] += x;
      __syncthreads();
    }
    int excl = (t > 0) ? s[t - 1] : 0;
    cur[t] = excl;
    int node = bin * 256 + t;
    if (node < N_NODES) offs[node] = base + excl;
    if (node == N_NODES) offs[N_NODES] = E_EDGES;
    __syncthreads();
    for (int i = t; i < cnt; i += 256) {
      int p = stg[i];
      int r = atomicAdd(&cur[(p >> 20) & 255], 1);
      stg2[r] = p & 0xFFFFF;
    }
    __syncthreads();
    // per-node ascending insertion sort (thread t owns node t's segment)
    {
      int len = h[t];
      int beg = excl;
      for (int a = 1; a < len; ++a) {
        int key = stg2[beg + a];
        int b = a - 1;
        while (b >= 0 && stg2[beg + b] > key) {
          stg2[beg + b + 1] = stg2[beg + b];
          --b;
        }
        stg2[beg + b + 1] = key;
      }
    }
    __syncthreads();
    // coalesced write-out
    for (int i = t; i < cnt; i += 256) srcidx[base + i] = stg2[i];
  } else {
    // ---- fallback: original two-pass global path (unsorted) ----
    for (int i = base + t; i < end; i += 256)
      atomicAdd(&h[(binned[i] >> 20) & 255], 1);
    __syncthreads();
    s[t] = h[t];
    __syncthreads();
    #pragma unroll
    for (int off = 1; off < 256; off <<= 1) {
      int x = (t >= off) ? s[t - off] : 0;
      __syncthreads();
      s[t] += x;
      __syncthreads();
    }
    int excl = (t > 0) ? s[t - 1] : 0;
    cur[t] = excl;
    int node = bin * 256 + t;
    if (node < N_NODES) offs[node] = base + excl;
    if (node == N_NODES) offs[N_NODES] = E_EDGES;
    __syncthreads();
    for (int i = base + t; i < end; i += 256) {
      int p = binned[i];
      int r = atomicAdd(&cur[(p >> 20) & 255], 1);
      srcidx[base + r] = p & 0xFFFFF;
    }
  }
}

// ---------------- gather + mean -> aggb (bf16): proven, 50K waves ------------
__global__ __launch_bounds__(256) void k_gather(const unsigned* __restrict__ hb,
                                                const int* __restrict__ offs,
                                                const int* __restrict__ srcidx,
                                                unsigned* __restrict__ aggb) {
  int wave = threadIdx.x >> 6;
  int lane = threadIdx.x & 63;
  int n0 = blockIdx.x * 8 + wave * 2;
  int n1 = n0 + 1;
  int b0 = __builtin_amdgcn_readfirstlane(offs[n0]);
  int e0 = __builtin_amdgcn_readfirstlane(offs[n0 + 1]);
  int b1 = __builtin_amdgcn_readfirstlane(offs[n1]);
  int e1 = __builtin_amdgcn_readfirstlane(offs[n1 + 1]);
  int m0 = e0 - b0, m1 = e1 - b1;
  int c  = (m0 < m1 ? m0 : m1) & ~7;   // common interleaved part

  float ax0 = 0.0f, ay0 = 0.0f, ax1 = 0.0f, ay1 = 0.0f;

  // interleaved: 16 outstanding loads (8 per chain)
  for (int j = 0; j < c; j += 8) {
    unsigned p0[8], p1[8];
    #pragma unroll
    for (int i = 0; i < 8; ++i) {
      int s0 = srcidx[b0 + j + i];
      int s1 = srcidx[b1 + j + i];
      p0[i] = hb[(size_t)s0 * 64 + lane];
      p1[i] = hb[(size_t)s1 * 64 + lane];
    }
    #pragma unroll
    for (int i = 0; i < 8; ++i) {
      float2 v0 = bf16unpack(p0[i]);
      float2 v1 = bf16unpack(p1[i]);
      ax0 += v0.x; ay0 += v0.y;
      ax1 += v1.x; ay1 += v1.y;
    }
  }
  for (int j = b0 + c; j < e0; ) {
    int rem = e0 - j;
    if (rem >= 8) {
      unsigned p[8];
      #pragma unroll
      for (int i = 0; i < 8; ++i) p[i] = hb[(size_t)srcidx[j + i] * 64 + lane];
      #pragma unroll
      for (int i = 0; i < 8; ++i) { float2 v = bf16unpack(p[i]); ax0 += v.x; ay0 += v.y; }
      j += 8;
    } else {
      float2 v = bf16unpack(hb[(size_t)srcidx[j] * 64 + lane]);
      ax0 += v.x; ay0 += v.y;
      ++j;
    }
  }
  for (int j = b1 + c; j < e1; ) {
    int rem = e1 - j;
    if (rem >= 8) {
      unsigned p[8];
      #pragma unroll
      for (int i = 0; i < 8; ++i) p[i] = hb[(size_t)srcidx[j + i] * 64 + lane];
      #pragma unroll
      for (int i = 0; i < 8; ++i) { float2 v = bf16unpack(p[i]); ax1 += v.x; ay1 += v.y; }
      j += 8;
    } else {
      float2 v = bf16unpack(hb[(size_t)srcidx[j] * 64 + lane]);
      ax1 += v.x; ay1 += v.y;
      ++j;
    }
  }

  float inv0 = 1.0f / fmaxf((float)m0, 1.0f);
  float inv1 = 1.0f / fmaxf((float)m1, 1.0f);
  aggb[(size_t)n0 * 64 + lane] = bf16pack(ax0 * inv0, ay0 * inv0);
  aggb[(size_t)n1 * 64 + lane] = bf16pack(ax1 * inv1, ay1 * inv1);
}

// ---------------- bf16 MFMA GEMM: out = [aggb|hb] @ WcatT^T + b_l ------------
__global__ __launch_bounds__(256) void k_gemm(const unsigned* __restrict__ aggb,
                                              const unsigned* __restrict__ hb,
                                              const unsigned* __restrict__ wtb,
                                              const float* __restrict__ bl,
                                              float* __restrict__ out) {
  int wave = threadIdx.x >> 6;
  int lane = threadIdx.x & 63;
  int m = lane & 15;
  int q = lane >> 4;
  int r0 = blockIdx.x * 64 + wave * 16;
  int rowA = r0 + m;
  if (rowA > N_NODES - 1) rowA = N_NODES - 1;  // tail clamp (stores guarded)

  const uint4* ar = (const uint4*)(aggb + (size_t)rowA * 64);
  const uint4* hr = (const uint4*)(hb + (size_t)rowA * 64);
  short8 afrag[8];
  #pragma unroll
  for (int kb = 0; kb < 4; ++kb) {
    uint4 u = ar[kb * 4 + q];
    afrag[kb] = *(short8*)&u;
  }
  #pragma unroll
  for (int kb = 0; kb < 4; ++kb) {
    uint4 u = hr[kb * 4 + q];
    afrag[kb + 4] = *(short8*)&u;
  }

  const uint4* b4 = (const uint4*)wtb;
  #pragma unroll
  for (int ct = 0; ct < 8; ++ct) {
    int c = ct * 16 + m;
    floatx4 acc = {0.0f, 0.0f, 0.0f, 0.0f};
    #pragma unroll
    for (int kb = 0; kb < 8; ++kb) {
      uint4 u = b4[kb * 512 + c * 4 + q];
      short8 bfrag = *(short8*)&u;
      acc = __builtin_amdgcn_mfma_f32_16x16x32_bf16(afrag[kb], bfrag, acc, 0, 0, 0);
    }
    float bias = bl[c];
    #pragma unroll
    for (int reg = 0; reg < 4; ++reg) {
      int r = r0 + q * 4 + reg;
      if (r < N_NODES) out[(size_t)r * DIM + c] = acc[reg] + bias;
    }
  }
}

extern "C" void kernel_launch(void* const* d_in, const int* in_sizes, int n_in,
                              void* d_out, int out_size, void* d_ws, size_t ws_size,
                              hipStream_t stream) {
  const float* x  = (const float*)d_in[0];
  const int*   ei = (const int*)d_in[1];   // [2, E] int32
  const float* lw = (const float*)d_in[2];
  const float* lb = (const float*)d_in[3];
  const float* Wl = (const float*)d_in[4];
  const float* bl = (const float*)d_in[5];
  const float* Wr = (const float*)d_in[6];
  float* out = (float*)d_out;

  char* ws = (char*)d_ws;
  unsigned* hb     = (unsigned*)(ws + HB_OFF);
  unsigned* wtb    = (unsigned*)(ws + WTB_OFF);
  int*      offs   = (int*)(ws + OFFS_OFF);
  int*      bhc    = (int*)(ws + BHC_OFF);
  int*      bh     = (int*)(ws + BH_OFF);
  int*      bsum   = (int*)(ws + BSUM_OFF);
  int*      binned = (int*)(ws + BIN_OFF);
  int*      srcidx = (int*)(ws + SRC_OFF);
  unsigned* aggb   = (unsigned*)(ws + AGGB_OFF);

  k_prep<<<N_NODES / 4, 256, 0, stream>>>(x, lw, lb, Wl, Wr, ei, hb, wtb, bhc);
  k_hscan1<<<HS_BLOCKS, 256, 0, stream>>>(bhc, bh, bsum);
  k_binsort<<<NB1, 256, 0, stream>>>(ei, bh, bhc, bsum, binned);
  k_csr<<<NBUCKET, 256, 0, stream>>>(bh, bsum, binned, offs, srcidx);
  k_gather<<<N_NODES / 8, 256, 0, stream>>>(hb, offs, srcidx, aggb);
  k_gemm<<<(N_NODES + 63) / 64, 256, 0, stream>>>(aggb, hb, wtb, bl, out);
}

// Round 13
// 254.441 us; speedup vs baseline: 1.1492x; 1.1492x over previous
//
#include <hip/hip_runtime.h>

#define N_NODES 100000
#define E_EDGES 1600000
#define DIM     128

// Binning geometry: bucket = 256 nodes (dst>>8), 391 real buckets pad 512;
// chunk = 4096 edges, 391 chunks. binned is CHUNK-LOCALLY bin-sorted; the
// global CSR base of bucket b is sum_ch ebase[b][ch] (no cross-chunk scan!).
#define NB1     391            // chunks
#define CHUNK   4096
#define NBINS   512            // padded bucket count (actual 391)
#define NBUCKET 391
#define NBH     (NBINS * NB1)  // 200192 bin-major [bin][chunk] entries

// Workspace layout (bytes), total ~66.1 MiB:
#define HB_OFF    0            // h packed bf16: N*64 u32 = 25,600,000
#define WTB_OFF   25600000     // WcatT bf16 B-fragment layout: 65,536
#define OFFS_OFF  25665536     // N+1 int (padded to 400,064)
#define BHC_OFF   26065600     // counts bhc[bin][chunk]: 800,768 (pad 800,832)
#define EBG_OFF   26866432     // chunk-local excl base ebg[bin][chunk]: 800,832
#define BIN_OFF   27667264     // E ints = 6,400,000 (chunk-locally sorted)
#define SRC_OFF   34067264     // E ints = 6,400,000
#define AGGB_OFF  40467264     // N*64 u32 = 25,600,000 -> end 66,067,264

typedef __attribute__((ext_vector_type(8))) short short8;
typedef __attribute__((ext_vector_type(4))) float floatx4;

// ---------- bf16 pack/unpack (RNE) ----------
__device__ __forceinline__ unsigned bf16pack(float a, float b) {
  unsigned ua = __float_as_uint(a); ua += 0x7fffu + ((ua >> 16) & 1u);
  unsigned ub = __float_as_uint(b); ub += 0x7fffu + ((ub >> 16) & 1u);
  return (ua >> 16) | (ub & 0xffff0000u);
}
__device__ __forceinline__ float2 bf16unpack(unsigned p) {
  return make_float2(__uint_as_float(p << 16), __uint_as_float(p & 0xffff0000u));
}

// ------------- prep: LayerNorm+ReLU -> hb, weight pack, level-1 histogram ----
__global__ __launch_bounds__(256) void k_prep(const float* __restrict__ x,
                                              const float* __restrict__ lw,
                                              const float* __restrict__ lb,
                                              const float* __restrict__ Wl,
                                              const float* __restrict__ Wr,
                                              const int* __restrict__ ei,
                                              unsigned* __restrict__ hb,
                                              unsigned* __restrict__ wtb,
                                              int* __restrict__ bhc) {
  int gid = blockIdx.x * 256 + threadIdx.x;
  int t = threadIdx.x;

  // --- LN+ReLU ---
  {
    int row  = blockIdx.x * 4 + (t >> 6);
    int lane = t & 63;
    float2 v = ((const float2*)(x + (size_t)row * DIM))[lane];
    float s  = v.x + v.y;
    float sq = v.x * v.x + v.y * v.y;
    #pragma unroll
    for (int off = 32; off > 0; off >>= 1) {
      s  += __shfl_xor(s, off);
      sq += __shfl_xor(sq, off);
    }
    float mu  = s * (1.0f / 128.0f);
    float var = sq * (1.0f / 128.0f) - mu * mu;
    float rs  = rsqrtf(var + 1e-5f);
    float2 w = ((const float2*)lw)[lane];
    float2 b = ((const float2*)lb)[lane];
    float ox = fmaxf((v.x - mu) * rs * w.x + b.x, 0.0f);
    float oy = fmaxf((v.y - mu) * rs * w.y + b.y, 0.0f);
    hb[(size_t)row * 64 + lane] = bf16pack(ox, oy);
  }

  // --- weight pack (bf16, B-fragment layout) ---
  if (gid < 16384) {
    int j2 = gid & 3;
    int q  = (gid >> 2) & 3;
    int c  = (gid >> 4) & 127;
    int kb = gid >> 11;
    int k0 = kb * 32 + q * 8 + j2 * 2;
    int k1 = k0 + 1;
    float v0 = (k0 < 128) ? Wl[c * 128 + k0] : Wr[c * 128 + (k0 - 128)];
    float v1 = (k1 < 128) ? Wl[c * 128 + k1] : Wr[c * 128 + (k1 - 128)];
    wtb[gid] = bf16pack(v0, v1);
  }

  // --- level-1 histogram: chunk = 4096 edges (block-uniform branch) ---
  if (blockIdx.x < NB1) {
    __shared__ int h[NBINS];
    h[t] = 0; h[t + 256] = 0;
    __syncthreads();
    const int4* d4p = (const int4*)(ei + E_EDGES);
    #pragma unroll
    for (int u = 0; u < 4; ++u) {
      int i4 = blockIdx.x * (CHUNK / 4) + u * 256 + t;
      if (i4 < E_EDGES / 4) {
        int4 d = d4p[i4];
        atomicAdd(&h[d.x >> 8], 1);
        atomicAdd(&h[d.y >> 8], 1);
        atomicAdd(&h[d.z >> 8], 1);
        atomicAdd(&h[d.w >> 8], 1);
      }
    }
    __syncthreads();
    bhc[t * NB1 + blockIdx.x] = h[t];
    bhc[(t + 256) * NB1 + blockIdx.x] = h[t + 256];
  }
}

// ------- bin-sort: chunk-LOCAL sort, contiguous coalesced write-out ----------
// Loads chunk counts from bhc (no pass-1 atomics), LDS-scans them, places
// edges at chunk-local positions, writes binned[ch*CHUNK + local] contiguously
// and ebg[bin][ch] (chunk-local exclusive base) for csr.
__global__ __launch_bounds__(256) void k_binsort(const int* __restrict__ ei,
                                                 const int* __restrict__ bhc,
                                                 int* __restrict__ binned,
                                                 int* __restrict__ ebg) {
  __shared__ int stage[CHUNK];   // 16 KiB
  __shared__ int hist[NBINS];
  __shared__ int ebase[NBINS];
  __shared__ int cur[NBINS];
  __shared__ int s[256];
  int t  = threadIdx.x;
  int ch = blockIdx.x;

  hist[t]       = bhc[t * NB1 + ch];
  hist[t + 256] = bhc[(t + 256) * NB1 + ch];
  __syncthreads();

  // scan 512 bins via 256 pair-partials (no atomics)
  int h0 = hist[2 * t], h1 = hist[2 * t + 1];
  s[t] = h0 + h1;
  __syncthreads();
  #pragma unroll
  for (int off = 1; off < 256; off <<= 1) {
    int xv = (t >= off) ? s[t - off] : 0;
    __syncthreads();
    s[t] += xv;
    __syncthreads();
  }
  int ex = (t > 0) ? s[t - 1] : 0;
  ebase[2 * t] = ex;
  ebase[2 * t + 1] = ex + h0;
  cur[2 * t] = ex;
  cur[2 * t + 1] = ex + h0;
  ebg[(2 * t) * NB1 + ch]     = ex;
  ebg[(2 * t + 1) * NB1 + ch] = ex + h0;
  __syncthreads();

  const int4* s4p = (const int4*)ei;
  const int4* d4p = (const int4*)(ei + E_EDGES);

  // place edges bin-sorted at chunk-local positions
  #pragma unroll
  for (int u = 0; u < 4; ++u) {
    int i4 = ch * (CHUNK / 4) + u * 256 + t;
    if (i4 < E_EDGES / 4) {
      int4 sv = s4p[i4];
      int4 dv = d4p[i4];
      {
        int bin = dv.x >> 8; int pos = atomicAdd(&cur[bin], 1);
        stage[pos] = sv.x | ((dv.x & 255) << 20);
      }
      {
        int bin = dv.y >> 8; int pos = atomicAdd(&cur[bin], 1);
        stage[pos] = sv.y | ((dv.y & 255) << 20);
      }
      {
        int bin = dv.z >> 8; int pos = atomicAdd(&cur[bin], 1);
        stage[pos] = sv.z | ((dv.z & 255) << 20);
      }
      {
        int bin = dv.w >> 8; int pos = atomicAdd(&cur[bin], 1);
        stage[pos] = sv.w | ((dv.w & 255) << 20);
      }
    }
  }
  __syncthreads();

  // contiguous coalesced write-out of the whole sorted chunk
  int cbase = ch * CHUNK;
  int cnt = E_EDGES - cbase;
  if (cnt > CHUNK) cnt = CHUNK;
  for (int i = t; i < cnt; i += 256)
    binned[cbase + i] = stage[i];
}

// ---- CSR: one block per bucket; base_b = sum_ch ebg[b][ch]; two-pass -------
__global__ __launch_bounds__(256) void k_csr(const int* __restrict__ bhc,
                                             const int* __restrict__ ebg,
                                             const int* __restrict__ binned,
                                             int* __restrict__ offs,
                                             int* __restrict__ srcidx) {
  __shared__ int h[256];
  __shared__ int s[256];
  __shared__ int cur[256];
  __shared__ int bhcRow[NB1];
  __shared__ int ebgRow[NB1];
  __shared__ int baseSh;
  int t = threadIdx.x;
  int b = blockIdx.x;

  for (int i = t; i < NB1; i += 256) {
    bhcRow[i] = bhc[b * NB1 + i];
    ebgRow[i] = ebg[b * NB1 + i];
  }
  h[t] = 0;
  __syncthreads();

  // base_b = sum over chunks of (entries before bucket b in chunk)
  {
    int p = 0;
    for (int i = t; i < NB1; i += 256) p += ebgRow[i];
    s[t] = p;
    __syncthreads();
    #pragma unroll
    for (int off = 128; off > 0; off >>= 1) {
      if (t < off) s[t] += s[t + off];
      __syncthreads();
    }
    if (t == 0) baseSh = s[0];
    __syncthreads();
  }
  int base = baseSh;

  // pass A: per-node histogram over this bucket's segments
  for (int ch = t; ch < NB1; ch += 256) {
    int st = ch * CHUNK + ebgRow[ch];
    int len = bhcRow[ch];
    for (int k = 0; k < len; ++k)
      atomicAdd(&h[(binned[st + k] >> 20) & 255], 1);
  }
  __syncthreads();

  // scan 256 node counts -> offs
  s[t] = h[t];
  __syncthreads();
  #pragma unroll
  for (int off = 1; off < 256; off <<= 1) {
    int x = (t >= off) ? s[t - off] : 0;
    __syncthreads();
    s[t] += x;
    __syncthreads();
  }
  int excl = (t > 0) ? s[t - 1] : 0;
  cur[t] = excl;
  int node = b * 256 + t;
  if (node < N_NODES) offs[node] = base + excl;
  if (node == N_NODES) offs[N_NODES] = E_EDGES;
  __syncthreads();

  // pass B: scatter srcs node-grouped
  for (int ch = t; ch < NB1; ch += 256) {
    int st = ch * CHUNK + ebgRow[ch];
    int len = bhcRow[ch];
    for (int k = 0; k < len; ++k) {
      int p = binned[st + k];
      int r = atomicAdd(&cur[(p >> 20) & 255], 1);
      srcidx[base + r] = p & 0xFFFFF;
    }
  }
}

// ---------------- gather + mean -> aggb (bf16): proven, 50K waves ------------
__global__ __launch_bounds__(256) void k_gather(const unsigned* __restrict__ hb,
                                                const int* __restrict__ offs,
                                                const int* __restrict__ srcidx,
                                                unsigned* __restrict__ aggb) {
  int wave = threadIdx.x >> 6;
  int lane = threadIdx.x & 63;
  int n0 = blockIdx.x * 8 + wave * 2;
  int n1 = n0 + 1;
  int b0 = __builtin_amdgcn_readfirstlane(offs[n0]);
  int e0 = __builtin_amdgcn_readfirstlane(offs[n0 + 1]);
  int b1 = __builtin_amdgcn_readfirstlane(offs[n1]);
  int e1 = __builtin_amdgcn_readfirstlane(offs[n1 + 1]);
  int m0 = e0 - b0, m1 = e1 - b1;
  int c  = (m0 < m1 ? m0 : m1) & ~7;   // common interleaved part

  float ax0 = 0.0f, ay0 = 0.0f, ax1 = 0.0f, ay1 = 0.0f;

  // interleaved: 16 outstanding loads (8 per chain)
  for (int j = 0; j < c; j += 8) {
    unsigned p0[8], p1[8];
    #pragma unroll
    for (int i = 0; i < 8; ++i) {
      int s0 = srcidx[b0 + j + i];
      int s1 = srcidx[b1 + j + i];
      p0[i] = hb[(size_t)s0 * 64 + lane];
      p1[i] = hb[(size_t)s1 * 64 + lane];
    }
    #pragma unroll
    for (int i = 0; i < 8; ++i) {
      float2 v0 = bf16unpack(p0[i]);
      float2 v1 = bf16unpack(p1[i]);
      ax0 += v0.x; ay0 += v0.y;
      ax1 += v1.x; ay1 += v1.y;
    }
  }
  for (int j = b0 + c; j < e0; ) {
    int rem = e0 - j;
    if (rem >= 8) {
      unsigned p[8];
      #pragma unroll
      for (int i = 0; i < 8; ++i) p[i] = hb[(size_t)srcidx[j + i] * 64 + lane];
      #pragma unroll
      for (int i = 0; i < 8; ++i) { float2 v = bf16unpack(p[i]); ax0 += v.x; ay0 += v.y; }
      j += 8;
    } else {
      float2 v = bf16unpack(hb[(size_t)srcidx[j] * 64 + lane]);
      ax0 += v.x; ay0 += v.y;
      ++j;
    }
  }
  for (int j = b1 + c; j < e1; ) {
    int rem = e1 - j;
    if (rem >= 8) {
      unsigned p[8];
      #pragma unroll
      for (int i = 0; i < 8; ++i) p[i] = hb[(size_t)srcidx[j + i] * 64 + lane];
      #pragma unroll
      for (int i = 0; i < 8; ++i) { float2 v = bf16unpack(p[i]); ax1 += v.x; ay1 += v.y; }
      j += 8;
    } else {
      float2 v = bf16unpack(hb[(size_t)srcidx[j] * 64 + lane]);
      ax1 += v.x; ay1 += v.y;
      ++j;
    }
  }

  float inv0 = 1.0f / fmaxf((float)m0, 1.0f);
  float inv1 = 1.0f / fmaxf((float)m1, 1.0f);
  aggb[(size_t)n0 * 64 + lane] = bf16pack(ax0 * inv0, ay0 * inv0);
  aggb[(size_t)n1 * 64 + lane] = bf16pack(ax1 * inv1, ay1 * inv1);
}

// ---------------- bf16 MFMA GEMM: out = [aggb|hb] @ WcatT^T + b_l ------------
__global__ __launch_bounds__(256) void k_gemm(const unsigned* __restrict__ aggb,
                                              const unsigned* __restrict__ hb,
                                              const unsigned* __restrict__ wtb,
                                              const float* __restrict__ bl,
                                              float* __restrict__ out) {
  int wave = threadIdx.x >> 6;
  int lane = threadIdx.x & 63;
  int m = lane & 15;
  int q = lane >> 4;
  int r0 = blockIdx.x * 64 + wave * 16;
  int rowA = r0 + m;
  if (rowA > N_NODES - 1) rowA = N_NODES - 1;  // tail clamp (stores guarded)

  const uint4* ar = (const uint4*)(aggb + (size_t)rowA * 64);
  const uint4* hr = (const uint4*)(hb + (size_t)rowA * 64);
  short8 afrag[8];
  #pragma unroll
  for (int kb = 0; kb < 4; ++kb) {
    uint4 u = ar[kb * 4 + q];
    afrag[kb] = *(short8*)&u;
  }
  #pragma unroll
  for (int kb = 0; kb < 4; ++kb) {
    uint4 u = hr[kb * 4 + q];
    afrag[kb + 4] = *(short8*)&u;
  }

  const uint4* b4 = (const uint4*)wtb;
  #pragma unroll
  for (int ct = 0; ct < 8; ++ct) {
    int c = ct * 16 + m;
    floatx4 acc = {0.0f, 0.0f, 0.0f, 0.0f};
    #pragma unroll
    for (int kb = 0; kb < 8; ++kb) {
      uint4 u = b4[kb * 512 + c * 4 + q];
      short8 bfrag = *(short8*)&u;
      acc = __builtin_amdgcn_mfma_f32_16x16x32_bf16(afrag[kb], bfrag, acc, 0, 0, 0);
    }
    float bias = bl[c];
    #pragma unroll
    for (int reg = 0; reg < 4; ++reg) {
      int r = r0 + q * 4 + reg;
      if (r < N_NODES) out[(size_t)r * DIM + c] = acc[reg] + bias;
    }
  }
}

extern "C" void kernel_launch(void* const* d_in, const int* in_sizes, int n_in,
                              void* d_out, int out_size, void* d_ws, size_t ws_size,
                              hipStream_t stream) {
  const float* x  = (const float*)d_in[0];
  const int*   ei = (const int*)d_in[1];   // [2, E] int32
  const float* lw = (const float*)d_in[2];
  const float* lb = (const float*)d_in[3];
  const float* Wl = (const float*)d_in[4];
  const float* bl = (const float*)d_in[5];
  const float* Wr = (const float*)d_in[6];
  float* out = (float*)d_out;

  char* ws = (char*)d_ws;
  unsigned* hb     = (unsigned*)(ws + HB_OFF);
  unsigned* wtb    = (unsigned*)(ws + WTB_OFF);
  int*      offs   = (int*)(ws + OFFS_OFF);
  int*      bhc    = (int*)(ws + BHC_OFF);
  int*      ebg    = (int*)(ws + EBG_OFF);
  int*      binned = (int*)(ws + BIN_OFF);
  int*      srcidx = (int*)(ws + SRC_OFF);
  unsigned* aggb   = (unsigned*)(ws + AGGB_OFF);

  k_prep<<<N_NODES / 4, 256, 0, stream>>>(x, lw, lb, Wl, Wr, ei, hb, wtb, bhc);
  k_binsort<<<NB1, 256, 0, stream>>>(ei, bhc, binned, ebg);
  k_csr<<<NBUCKET, 256, 0, stream>>>(bhc, ebg, binned, offs, srcidx);
  k_gather<<<N_NODES / 8, 256, 0, stream>>>(hb, offs, srcidx, aggb);
  k_gemm<<<(N_NODES + 63) / 64, 256, 0, stream>>>(aggb, hb, wtb, bl, out);
}

// Round 14
// 249.025 us; speedup vs baseline: 1.1741x; 1.0217x over previous
//
#include <hip/hip_runtime.h>

#define N_NODES 100000
#define E_EDGES 1600000
#define DIM     128

// Binning geometry: bucket = 256 nodes (dst>>8), 391 real buckets pad 512;
// chunk = 4096 edges, 391 chunks. binned is CHUNK-LOCALLY bin-sorted; the
// global CSR base of bucket b is sum_ch ebg[b][ch] (no cross-chunk scan).
#define NB1     391            // chunks
#define CHUNK   4096
#define NBINS   512            // padded bucket count (actual 391)
#define NBUCKET 391

// Workspace layout (bytes), total ~66.1 MiB:
#define HB_OFF    0            // h packed bf16: N*64 u32 = 25,600,000
#define WTB_OFF   25600000     // WcatT bf16 B-fragment layout: 65,536
#define OFFS_OFF  25665536     // N+1 int (padded to 400,064)
#define BHC_OFF   26065600     // counts bhc[bin][chunk]: 800,768 (pad 800,832)
#define EBG_OFF   26866432     // chunk-local excl base ebg[bin][chunk]: 800,832
#define BIN_OFF   27667264     // E ints = 6,400,000 (chunk-locally sorted)
#define SRC_OFF   34067264     // E ints = 6,400,000
#define AGGB_OFF  40467264     // N*64 u32 = 25,600,000 -> end 66,067,264

typedef __attribute__((ext_vector_type(8))) short short8;
typedef __attribute__((ext_vector_type(4))) float floatx4;

// ---------- bf16 pack/unpack (RNE) ----------
__device__ __forceinline__ unsigned bf16pack(float a, float b) {
  unsigned ua = __float_as_uint(a); ua += 0x7fffu + ((ua >> 16) & 1u);
  unsigned ub = __float_as_uint(b); ub += 0x7fffu + ((ub >> 16) & 1u);
  return (ua >> 16) | (ub & 0xffff0000u);
}
__device__ __forceinline__ float2 bf16unpack(unsigned p) {
  return make_float2(__uint_as_float(p << 16), __uint_as_float(p & 0xffff0000u));
}

// --- prep: LN+ReLU -> hb | weight pack | FUSED hist+scan+binsort (block ch) --
// Blocks 0..390 additionally bin-sort their own 4096-edge chunk entirely in
// LDS (hist -> scan -> place -> coalesced write-out). All block-local: the
// former k_binsort dispatch, its ei re-read, and its bhc load are deleted.
__global__ __launch_bounds__(256) void k_prep(const float* __restrict__ x,
                                              const float* __restrict__ lw,
                                              const float* __restrict__ lb,
                                              const float* __restrict__ Wl,
                                              const float* __restrict__ Wr,
                                              const int* __restrict__ ei,
                                              unsigned* __restrict__ hb,
                                              unsigned* __restrict__ wtb,
                                              int* __restrict__ bhc,
                                              int* __restrict__ ebg,
                                              int* __restrict__ binned) {
  __shared__ int h[NBINS];
  __shared__ int cur[NBINS];
  __shared__ int s[256];
  __shared__ int stage[CHUNK];   // 16 KiB
  int gid = blockIdx.x * 256 + threadIdx.x;
  int t = threadIdx.x;

  // --- LN+ReLU (all blocks) ---
  {
    int row  = blockIdx.x * 4 + (t >> 6);
    int lane = t & 63;
    float2 v = ((const float2*)(x + (size_t)row * DIM))[lane];
    float sx  = v.x + v.y;
    float sq = v.x * v.x + v.y * v.y;
    #pragma unroll
    for (int off = 32; off > 0; off >>= 1) {
      sx += __shfl_xor(sx, off);
      sq += __shfl_xor(sq, off);
    }
    float mu  = sx * (1.0f / 128.0f);
    float var = sq * (1.0f / 128.0f) - mu * mu;
    float rs  = rsqrtf(var + 1e-5f);
    float2 w = ((const float2*)lw)[lane];
    float2 b = ((const float2*)lb)[lane];
    float ox = fmaxf((v.x - mu) * rs * w.x + b.x, 0.0f);
    float oy = fmaxf((v.y - mu) * rs * w.y + b.y, 0.0f);
    hb[(size_t)row * 64 + lane] = bf16pack(ox, oy);
  }

  // --- weight pack (bf16, B-fragment layout) ---
  if (gid < 16384) {
    int j2 = gid & 3;
    int q  = (gid >> 2) & 3;
    int c  = (gid >> 4) & 127;
    int kb = gid >> 11;
    int k0 = kb * 32 + q * 8 + j2 * 2;
    int k1 = k0 + 1;
    float v0 = (k0 < 128) ? Wl[c * 128 + k0] : Wr[c * 128 + (k0 - 128)];
    float v1 = (k1 < 128) ? Wl[c * 128 + k1] : Wr[c * 128 + (k1 - 128)];
    wtb[gid] = bf16pack(v0, v1);
  }

  // --- fused hist + scan + bin-sort of chunk ch (block-uniform branch) ---
  if (blockIdx.x < NB1) {
    int ch = blockIdx.x;
    h[t] = 0; h[t + 256] = 0;
    __syncthreads();
    const int4* s4p = (const int4*)ei;
    const int4* d4p = (const int4*)(ei + E_EDGES);
    #pragma unroll
    for (int u = 0; u < 4; ++u) {
      int i4 = ch * (CHUNK / 4) + u * 256 + t;
      if (i4 < E_EDGES / 4) {
        int4 d = d4p[i4];
        atomicAdd(&h[d.x >> 8], 1);
        atomicAdd(&h[d.y >> 8], 1);
        atomicAdd(&h[d.z >> 8], 1);
        atomicAdd(&h[d.w >> 8], 1);
      }
    }
    __syncthreads();
    // write counts, scan 512 bins via 256 pair-partials
    int h0 = h[2 * t], h1 = h[2 * t + 1];
    bhc[(2 * t) * NB1 + ch]     = h0;
    bhc[(2 * t + 1) * NB1 + ch] = h1;
    s[t] = h0 + h1;
    __syncthreads();
    #pragma unroll
    for (int off = 1; off < 256; off <<= 1) {
      int xv = (t >= off) ? s[t - off] : 0;
      __syncthreads();
      s[t] += xv;
      __syncthreads();
    }
    int ex = (t > 0) ? s[t - 1] : 0;
    cur[2 * t] = ex;
    cur[2 * t + 1] = ex + h0;
    ebg[(2 * t) * NB1 + ch]     = ex;
    ebg[(2 * t + 1) * NB1 + ch] = ex + h0;
    __syncthreads();
    // place edges bin-sorted at chunk-local positions (ei re-read is L2-hot)
    #pragma unroll
    for (int u = 0; u < 4; ++u) {
      int i4 = ch * (CHUNK / 4) + u * 256 + t;
      if (i4 < E_EDGES / 4) {
        int4 sv = s4p[i4];
        int4 dv = d4p[i4];
        {
          int bin = dv.x >> 8; int pos = atomicAdd(&cur[bin], 1);
          stage[pos] = sv.x | ((dv.x & 255) << 20);
        }
        {
          int bin = dv.y >> 8; int pos = atomicAdd(&cur[bin], 1);
          stage[pos] = sv.y | ((dv.y & 255) << 20);
        }
        {
          int bin = dv.z >> 8; int pos = atomicAdd(&cur[bin], 1);
          stage[pos] = sv.z | ((dv.z & 255) << 20);
        }
        {
          int bin = dv.w >> 8; int pos = atomicAdd(&cur[bin], 1);
          stage[pos] = sv.w | ((dv.w & 255) << 20);
        }
      }
    }
    __syncthreads();
    // contiguous coalesced write-out of the sorted chunk
    int cbase = ch * CHUNK;
    int cnt = E_EDGES - cbase;
    if (cnt > CHUNK) cnt = CHUNK;
    for (int i = t; i < cnt; i += 256)
      binned[cbase + i] = stage[i];
  }
}

// ---- CSR: one block per bucket; base_b = sum_ch ebg[b][ch]; two-pass -------
__global__ __launch_bounds__(256) void k_csr(const int* __restrict__ bhc,
                                             const int* __restrict__ ebg,
                                             const int* __restrict__ binned,
                                             int* __restrict__ offs,
                                             int* __restrict__ srcidx) {
  __shared__ int h[256];
  __shared__ int s[256];
  __shared__ int cur[256];
  __shared__ int bhcRow[NB1];
  __shared__ int ebgRow[NB1];
  __shared__ int baseSh;
  int t = threadIdx.x;
  int b = blockIdx.x;

  for (int i = t; i < NB1; i += 256) {
    bhcRow[i] = bhc[b * NB1 + i];
    ebgRow[i] = ebg[b * NB1 + i];
  }
  h[t] = 0;
  __syncthreads();

  // base_b = sum over chunks of (entries before bucket b in chunk)
  {
    int p = 0;
    for (int i = t; i < NB1; i += 256) p += ebgRow[i];
    s[t] = p;
    __syncthreads();
    #pragma unroll
    for (int off = 128; off > 0; off >>= 1) {
      if (t < off) s[t] += s[t + off];
      __syncthreads();
    }
    if (t == 0) baseSh = s[0];
    __syncthreads();
  }
  int base = baseSh;

  // pass A: per-node histogram over this bucket's segments
  for (int ch = t; ch < NB1; ch += 256) {
    int st = ch * CHUNK + ebgRow[ch];
    int len = bhcRow[ch];
    for (int k = 0; k < len; ++k)
      atomicAdd(&h[(binned[st + k] >> 20) & 255], 1);
  }
  __syncthreads();

  // scan 256 node counts -> offs
  s[t] = h[t];
  __syncthreads();
  #pragma unroll
  for (int off = 1; off < 256; off <<= 1) {
    int x = (t >= off) ? s[t - off] : 0;
    __syncthreads();
    s[t] += x;
    __syncthreads();
  }
  int excl = (t > 0) ? s[t - 1] : 0;
  cur[t] = excl;
  int node = b * 256 + t;
  if (node < N_NODES) offs[node] = base + excl;
  if (node == N_NODES) offs[N_NODES] = E_EDGES;
  __syncthreads();

  // pass B: scatter srcs node-grouped
  for (int ch = t; ch < NB1; ch += 256) {
    int st = ch * CHUNK + ebgRow[ch];
    int len = bhcRow[ch];
    for (int k = 0; k < len; ++k) {
      int p = binned[st + k];
      int r = atomicAdd(&cur[(p >> 20) & 255], 1);
      srcidx[base + r] = p & 0xFFFFF;
    }
  }
}

// ---- gather + mean -> aggb: 50K waves, srcidx PREFETCHED one iter ahead ----
// Per iteration the chain was srcidx(L2,~200cy) -> hb(~900cy), serialized.
// Prefetching the next iteration's 16 indices while hb loads are in flight
// removes srcidx latency from the critical path.
__global__ __launch_bounds__(256) void k_gather(const unsigned* __restrict__ hb,
                                                const int* __restrict__ offs,
                                                const int* __restrict__ srcidx,
                                                unsigned* __restrict__ aggb) {
  int wave = threadIdx.x >> 6;
  int lane = threadIdx.x & 63;
  int n0 = blockIdx.x * 8 + wave * 2;
  int n1 = n0 + 1;
  int b0 = __builtin_amdgcn_readfirstlane(offs[n0]);
  int e0 = __builtin_amdgcn_readfirstlane(offs[n0 + 1]);
  int b1 = __builtin_amdgcn_readfirstlane(offs[n1]);
  int e1 = __builtin_amdgcn_readfirstlane(offs[n1 + 1]);
  int m0 = e0 - b0, m1 = e1 - b1;
  int c  = (m0 < m1 ? m0 : m1) & ~7;   // common interleaved part

  float ax0 = 0.0f, ay0 = 0.0f, ax1 = 0.0f, ay1 = 0.0f;

  if (c > 0) {
    int sA[8], sB[8];
    #pragma unroll
    for (int i = 0; i < 8; ++i) {
      sA[i] = srcidx[b0 + i];
      sB[i] = srcidx[b1 + i];
    }
    for (int j = 0; j < c; j += 8) {
      unsigned p0[8], p1[8];
      #pragma unroll
      for (int i = 0; i < 8; ++i) {
        p0[i] = hb[(size_t)sA[i] * 64 + lane];
        p1[i] = hb[(size_t)sB[i] * 64 + lane];
      }
      if (j + 8 < c) {               // wave-uniform branch (c, j uniform)
        #pragma unroll
        for (int i = 0; i < 8; ++i) {
          sA[i] = srcidx[b0 + j + 8 + i];
          sB[i] = srcidx[b1 + j + 8 + i];
        }
      }
      #pragma unroll
      for (int i = 0; i < 8; ++i) {
        float2 v0 = bf16unpack(p0[i]);
        float2 v1 = bf16unpack(p1[i]);
        ax0 += v0.x; ay0 += v0.y;
        ax1 += v1.x; ay1 += v1.y;
      }
    }
  }
  for (int j = b0 + c; j < e0; ) {
    int rem = e0 - j;
    if (rem >= 8) {
      unsigned p[8];
      #pragma unroll
      for (int i = 0; i < 8; ++i) p[i] = hb[(size_t)srcidx[j + i] * 64 + lane];
      #pragma unroll
      for (int i = 0; i < 8; ++i) { float2 v = bf16unpack(p[i]); ax0 += v.x; ay0 += v.y; }
      j += 8;
    } else {
      float2 v = bf16unpack(hb[(size_t)srcidx[j] * 64 + lane]);
      ax0 += v.x; ay0 += v.y;
      ++j;
    }
  }
  for (int j = b1 + c; j < e1; ) {
    int rem = e1 - j;
    if (rem >= 8) {
      unsigned p[8];
      #pragma unroll
      for (int i = 0; i < 8; ++i) p[i] = hb[(size_t)srcidx[j + i] * 64 + lane];
      #pragma unroll
      for (int i = 0; i < 8; ++i) { float2 v = bf16unpack(p[i]); ax1 += v.x; ay1 += v.y; }
      j += 8;
    } else {
      float2 v = bf16unpack(hb[(size_t)srcidx[j] * 64 + lane]);
      ax1 += v.x; ay1 += v.y;
      ++j;
    }
  }

  float inv0 = 1.0f / fmaxf((float)m0, 1.0f);
  float inv1 = 1.0f / fmaxf((float)m1, 1.0f);
  aggb[(size_t)n0 * 64 + lane] = bf16pack(ax0 * inv0, ay0 * inv0);
  aggb[(size_t)n1 * 64 + lane] = bf16pack(ax1 * inv1, ay1 * inv1);
}

// ---------------- bf16 MFMA GEMM: out = [aggb|hb] @ WcatT^T + b_l ------------
__global__ __launch_bounds__(256) void k_gemm(const unsigned* __restrict__ aggb,
                                              const unsigned* __restrict__ hb,
                                              const unsigned* __restrict__ wtb,
                                              const float* __restrict__ bl,
                                              float* __restrict__ out) {
  int wave = threadIdx.x >> 6;
  int lane = threadIdx.x & 63;
  int m = lane & 15;
  int q = lane >> 4;
  int r0 = blockIdx.x * 64 + wave * 16;
  int rowA = r0 + m;
  if (rowA > N_NODES - 1) rowA = N_NODES - 1;  // tail clamp (stores guarded)

  const uint4* ar = (const uint4*)(aggb + (size_t)rowA * 64);
  const uint4* hr = (const uint4*)(hb + (size_t)rowA * 64);
  short8 afrag[8];
  #pragma unroll
  for (int kb = 0; kb < 4; ++kb) {
    uint4 u = ar[kb * 4 + q];
    afrag[kb] = *(short8*)&u;
  }
  #pragma unroll
  for (int kb = 0; kb < 4; ++kb) {
    uint4 u = hr[kb * 4 + q];
    afrag[kb + 4] = *(short8*)&u;
  }

  const uint4* b4 = (const uint4*)wtb;
  #pragma unroll
  for (int ct = 0; ct < 8; ++ct) {
    int c = ct * 16 + m;
    floatx4 acc = {0.0f, 0.0f, 0.0f, 0.0f};
    #pragma unroll
    for (int kb = 0; kb < 8; ++kb) {
      uint4 u = b4[kb * 512 + c * 4 + q];
      short8 bfrag = *(short8*)&u;
      acc = __builtin_amdgcn_mfma_f32_16x16x32_bf16(afrag[kb], bfrag, acc, 0, 0, 0);
    }
    float bias = bl[c];
    #pragma unroll
    for (int reg = 0; reg < 4; ++reg) {
      int r = r0 + q * 4 + reg;
      if (r < N_NODES) out[(size_t)r * DIM + c] = acc[reg] + bias;
    }
  }
}

extern "C" void kernel_launch(void* const* d_in, const int* in_sizes, int n_in,
                              void* d_out, int out_size, void* d_ws, size_t ws_size,
                              hipStream_t stream) {
  const float* x  = (const float*)d_in[0];
  const int*   ei = (const int*)d_in[1];   // [2, E] int32
  const float* lw = (const float*)d_in[2];
  const float* lb = (const float*)d_in[3];
  const float* Wl = (const float*)d_in[4];
  const float* bl = (const float*)d_in[5];
  const float* Wr = (const float*)d_in[6];
  float* out = (float*)d_out;

  char* ws = (char*)d_ws;
  unsigned* hb     = (unsigned*)(ws + HB_OFF);
  unsigned* wtb    = (unsigned*)(ws + WTB_OFF);
  int*      offs   = (int*)(ws + OFFS_OFF);
  int*      bhc    = (int*)(ws + BHC_OFF);
  int*      ebg    = (int*)(ws + EBG_OFF);
  int*      binned = (int*)(ws + BIN_OFF);
  int*      srcidx = (int*)(ws + SRC_OFF);
  unsigned* aggb   = (unsigned*)(ws + AGGB_OFF);

  k_prep<<<N_NODES / 4, 256, 0, stream>>>(x, lw, lb, Wl, Wr, ei, hb, wtb, bhc, ebg, binned);
  k_csr<<<NBUCKET, 256, 0, stream>>>(bhc, ebg, binned, offs, srcidx);
  k_gather<<<N_NODES / 8, 256, 0, stream>>>(hb, offs, srcidx, aggb);
  k_gemm<<<(N_NODES + 63) / 64, 256, 0, stream>>>(aggb, hb, wtb, bl, out);
}